// Round 11
// baseline (887.748 us; speedup 1.0000x reference)
//
#include <hip/hip_runtime.h>
#include <hip/hip_bf16.h>

// Shapes (fixed): B=4, S=8192, D_MODEL=1024, NHEAD=16, D_K=64, D_CHUNK=128,
// C=64 chunks. M = B*S = 32768 rows for all GEMMs, K=N=1024.

typedef __attribute__((ext_vector_type(8))) short short8;   // 8 bf16 (MFMA A/B frag)
typedef __attribute__((ext_vector_type(4))) float f32x4;    // MFMA C/D frag
typedef __attribute__((ext_vector_type(4))) unsigned short us4;
typedef __attribute__((ext_vector_type(4))) unsigned int u32x4;
typedef __attribute__((ext_vector_type(2))) unsigned int u32x2;

__device__ __forceinline__ unsigned short f2bf(float f) {
  unsigned u = __float_as_uint(f);
  u += 0x7fffu + ((u >> 16) & 1u);          // RNE round to bf16
  return (unsigned short)(u >> 16);
}

// HW packed convert: low16 = bf16(lo), high16 = bf16(hi).
__device__ __forceinline__ unsigned cvtpk(float lo, float hi) {
  unsigned r;
  asm("v_cvt_pk_bf16_f32 %0, %1, %2" : "=v"(r) : "v"(lo), "v"(hi));
  return r;
}

__device__ __forceinline__ void gload16(const void* g, void* l) {
  __builtin_amdgcn_global_load_lds((const __attribute__((address_space(1))) void*)g,
                                   (__attribute__((address_space(3))) void*)l, 16, 0, 0);
}

// ---------------- fp32 -> bf16 (4 weight matrices, one dispatch) ----------------
__global__ void f2b4_kernel(const float* __restrict__ i0, const float* __restrict__ i1,
                            const float* __restrict__ i2, const float* __restrict__ i3,
                            unsigned short* __restrict__ o0, unsigned short* __restrict__ o1,
                            unsigned short* __restrict__ o2, unsigned short* __restrict__ o3,
                            int n) {
  const int z = blockIdx.z;
  const float* in = z == 0 ? i0 : z == 1 ? i1 : z == 2 ? i2 : i3;
  unsigned short* out = z == 0 ? o0 : z == 1 ? o1 : z == 2 ? o2 : o3;
  int i = (blockIdx.x * 256 + threadIdx.x) * 4;
  if (i >= n) return;
  f32x4 x = *(const f32x4*)(in + i);
  u32x2 o;
  o[0] = cvtpk(x[0], x[1]);
  o[1] = cvtpk(x[2], x[3]);
  *(u32x2*)(out + i) = o;
}

// ---------------- GEMM core: C[M,1024] = A[M,1024] * B[1024,1024]^T + bias ----
// 256x256 tile, BK=64, 512 threads = 8 waves (2M x 4N), per-wave output 128x64.
// 8-phase schedule. Per K-tile t: 4 phases x {ds_read subtile; stage;
// s_barrier; setprio(1); 16 MFMA; setprio(0); s_barrier}.
//
// A_F32=false (round-8 proven): A(t+1) via global_load_lds at P0/P1; B(t+2)
// at P2/P3; counted vmcnt(4) at P3 drains A(t+1), leaves B(t+2) in flight.
//
// A_F32=true (fused fp32->bf16, depth-2 A prefetch): A(t+2) fp32 -> regs at
// t.P0 into buffer parity (t+2)&1 (loop unrolled x2 -> static buffer names,
// rule 20); cvt_pk+ds_write of A(t+1) from the OTHER buffer at t.P2/P3 —
// those loads were issued at (t-1).P0, 6 phases (~1000+ cyc) earlier, so the
// data-dep wait is free. B(t+1) (issued t-1.P2/P3, YOUNGER than A(t+1)'s
// loads) is drained by an explicit vmcnt(12) at t.P3 — leaves A(t+2) 8 +
// B(t+2) 4 in flight. FIFO check: steady-state outstanding at t.P3 after the
// writeA data-dep = B(t+1)4 + A(t+2)8 + B(t+2)4 = 16 -> vmcnt(12) drains
// exactly B(t+1). Tails: t=NT-2 -> vmcnt(0); t=NT-1 -> none. vmcnt purity:
// bias preloaded up front; no other VMEM in the loop body.
// T2: LDS dest linear; XOR swizzle g^(row&7) on the GLOBAL source granule
// and identically on ds_read (rule 21). Epilogue: coalesced C stores via
// wave-private LDS bounce.
template<bool A_F32, bool C_F32>
__device__ __forceinline__ void gemm_core(const void* __restrict__ Apv,
                                          const unsigned short* __restrict__ Bp,
                                          const float* __restrict__ bias,
                                          void* __restrict__ Cp) {
  constexpr int BK = 64, NT = 16;
  const int tid = threadIdx.x;              // 0..511
  const int lane = tid & 63, wave = tid >> 6;
  const int lg = lane >> 4, li = lane & 15;
  const int wr = wave >> 2, wc = wave & 3;  // 2 x 4 wave grid

  const unsigned short* Ab = (const unsigned short*)Apv;  // bf16 path
  const float* Af = (const float*)Apv;                    // fp32 path

  // XCD swizzle (nwg = 512, divisible by 8 -> bijective).
  const int orig = blockIdx.y * 4 + blockIdx.x;
  const int wg = (orig & 7) * 64 + (orig >> 3);
  const int bn = wg & 3, bm = wg >> 2;

  const long arow0 = (long)bm * 256;
  const int bcol0 = bn * 256;

  __shared__ __align__(16) unsigned short As[2][256 * BK];  // 64 KB
  __shared__ __align__(16) unsigned short Bs[2][256 * BK];  // 64 KB

  float bv[4];
  #pragma unroll
  for (int n = 0; n < 4; ++n) bv[n] = bias[bcol0 + wc * 64 + n * 16 + li];

  f32x4 acc[8][4];
  #pragma unroll
  for (int m = 0; m < 8; ++m)
    #pragma unroll
    for (int n = 0; n < 4; ++n) acc[m][n] = (f32x4){0.f, 0.f, 0.f, 0.f};

  // Stage one half-tile via global_load_lds: h = 0:A-lo 1:A-hi 2:B-lo 3:B-hi.
  auto stage_half = [&](int u, int h) {
    const int k0 = u * BK;
    const int half = h & 1;
    unsigned short* dst = (h < 2 ? As[u & 1] : Bs[u & 1]) + half * (128 * BK);
    const unsigned short* src = (h < 2) ? Ab : Bp;
    const long rbase = (h < 2) ? (arow0 + half * 128) : (long)(bcol0 + half * 128);
    #pragma unroll
    for (int it = 0; it < 2; ++it) {
      int s = it * 512 + tid;              // 0..1023
      int row = s >> 3;
      int eg = ((s & 7) ^ (row & 7)) * 8;  // pre-swizzled source granule
      gload16(src + (rbase + row) * 1024 + k0 + eg, (unsigned char*)dst + s * 16);
    }
  };

  // fp32-A register staging, DOUBLE-buffered (aregE/aregO, static names).
  f32x4 aregE[4][2], aregO[4][2];
  auto issueA = [&](int u, f32x4 (&ar)[4][2]) {
    #pragma unroll
    for (int hf = 0; hf < 2; ++hf)
      #pragma unroll
      for (int it = 0; it < 2; ++it) {
        int s = it * 512 + tid;
        int row = s >> 3;
        int ce = ((s & 7) ^ (row & 7)) * 8;
        const float* p = Af + (arow0 + hf * 128 + row) * 1024 + u * BK + ce;
        ar[hf * 2 + it][0] = *(const f32x4*)p;
        ar[hf * 2 + it][1] = *(const f32x4*)(p + 4);
      }
  };
  // hf passed as literal -> constant-propagated; 8 cvt_pk + 2 ds_write_b128.
  auto writeAh = [&](int u, int hf, f32x4 (&ar)[4][2]) {
    unsigned short* dstb = As[u & 1] + hf * (128 * BK);
    #pragma unroll
    for (int it = 0; it < 2; ++it) {
      int s = it * 512 + tid;
      u32x4 o;
      o[0] = cvtpk(ar[hf * 2 + it][0][0], ar[hf * 2 + it][0][1]);
      o[1] = cvtpk(ar[hf * 2 + it][0][2], ar[hf * 2 + it][0][3]);
      o[2] = cvtpk(ar[hf * 2 + it][1][0], ar[hf * 2 + it][1][1]);
      o[3] = cvtpk(ar[hf * 2 + it][1][2], ar[hf * 2 + it][1][3]);
      *(u32x4*)((unsigned char*)dstb + s * 16) = o;
    }
  };

  // One K-tile (8-phase). arI: buffer receiving A(t+2); arW: buffer holding
  // A(t+1) to cvt+write. Static parity via the x2-unrolled caller.
  auto tile_body = [&](int t, f32x4 (&arI)[4][2], f32x4 (&arW)[4][2]) {
    const unsigned short* Asb = As[t & 1];
    const unsigned short* Bsb = Bs[t & 1];

    auto LDA = [&](int m, int kk) {
      return *(const short8*)(Asb + (wr * 128 + m * 16 + li) * BK +
                              (((kk * 4 + lg) ^ (li & 7)) * 8));
    };
    auto LDB = [&](int n, int kk) {
      return *(const short8*)(Bsb + (wc * 64 + n * 16 + li) * BK +
                              (((kk * 4 + lg) ^ (li & 7)) * 8));
    };

    short8 b0[4], b1[4];

    // ---- P0 ----
    {
      short8 a0[4];
      #pragma unroll
      for (int i = 0; i < 4; ++i) a0[i] = LDA(i, 0);
      #pragma unroll
      for (int n = 0; n < 4; ++n) b0[n] = LDB(n, 0);
      if constexpr (A_F32) {
        if (t + 2 < NT) issueA(t + 2, arI);
      } else {
        if (t + 1 < NT) stage_half(t + 1, 0);
      }
      __builtin_amdgcn_s_barrier();
      __builtin_amdgcn_s_setprio(1);
      #pragma unroll
      for (int i = 0; i < 4; ++i)
        #pragma unroll
        for (int n = 0; n < 4; ++n)
          acc[i][n] = __builtin_amdgcn_mfma_f32_16x16x32_bf16(a0[i], b0[n], acc[i][n], 0, 0, 0);
      __builtin_amdgcn_s_setprio(0);
      __builtin_amdgcn_s_barrier();
    }
    // ---- P1 ----
    {
      short8 a1[4];
      #pragma unroll
      for (int i = 0; i < 4; ++i) a1[i] = LDA(i, 1);
      #pragma unroll
      for (int n = 0; n < 4; ++n) b1[n] = LDB(n, 1);
      if constexpr (!A_F32) {
        if (t + 1 < NT) stage_half(t + 1, 1);
      }
      __builtin_amdgcn_s_barrier();
      __builtin_amdgcn_s_setprio(1);
      #pragma unroll
      for (int i = 0; i < 4; ++i)
        #pragma unroll
        for (int n = 0; n < 4; ++n)
          acc[i][n] = __builtin_amdgcn_mfma_f32_16x16x32_bf16(a1[i], b1[n], acc[i][n], 0, 0, 0);
      __builtin_amdgcn_s_setprio(0);
      __builtin_amdgcn_s_barrier();
    }
    // ---- P2 ----
    {
      short8 a2[4];
      #pragma unroll
      for (int i = 0; i < 4; ++i) a2[i] = LDA(4 + i, 0);
      if (t + 2 < NT) stage_half(t + 2, 2);
      __builtin_amdgcn_s_barrier();
      __builtin_amdgcn_s_setprio(1);
      #pragma unroll
      for (int i = 0; i < 4; ++i)
        #pragma unroll
        for (int n = 0; n < 4; ++n)
          acc[4 + i][n] = __builtin_amdgcn_mfma_f32_16x16x32_bf16(a2[i], b0[n], acc[4 + i][n], 0, 0, 0);
      if constexpr (A_F32) {            // data-dep wait ~free: loads are 6 phases old
        if (t + 1 < NT) writeAh(t + 1, 0, arW);
      }
      __builtin_amdgcn_s_setprio(0);
      __builtin_amdgcn_s_barrier();
    }
    // ---- P3 ----
    {
      short8 a3[4];
      #pragma unroll
      for (int i = 0; i < 4; ++i) a3[i] = LDA(4 + i, 1);
      if (t + 2 < NT) stage_half(t + 2, 3);
      if constexpr (!A_F32) {
        if (t + 2 < NT) {
          asm volatile("s_waitcnt vmcnt(4)" ::: "memory");   // A(t+1) landed
        } else {
          asm volatile("s_waitcnt vmcnt(0)" ::: "memory");
        }
        __builtin_amdgcn_sched_barrier(0);
      }
      __builtin_amdgcn_s_barrier();
      __builtin_amdgcn_s_setprio(1);
      #pragma unroll
      for (int i = 0; i < 4; ++i)
        #pragma unroll
        for (int n = 0; n < 4; ++n)
          acc[4 + i][n] = __builtin_amdgcn_mfma_f32_16x16x32_bf16(a3[i], b1[n], acc[4 + i][n], 0, 0, 0);
      if constexpr (A_F32) {
        if (t + 1 < NT) {
          writeAh(t + 1, 1, arW);
          if (t + 2 < NT) {
            asm volatile("s_waitcnt vmcnt(12)" ::: "memory");  // drain B(t+1)
          } else {
            asm volatile("s_waitcnt vmcnt(0)" ::: "memory");
          }
          __builtin_amdgcn_sched_barrier(0);
          asm volatile("s_waitcnt lgkmcnt(0)" ::: "memory");   // publish A(t+1)
          __builtin_amdgcn_sched_barrier(0);
        }
      }
      __builtin_amdgcn_s_setprio(0);
      __builtin_amdgcn_s_barrier();                            // tile t+1 ready
    }
  };

  // ---- prologue ----
  if constexpr (A_F32) {
    issueA(0, aregE);                     // 8 loads (oldest)
    stage_half(0, 2); stage_half(0, 3);   // B(0) 4
    issueA(1, aregO);                     // 8
    stage_half(1, 2); stage_half(1, 3);   // B(1) 4
    writeAh(0, 0, aregE); writeAh(0, 1, aregE);  // data-dep drains A(0)
    asm volatile("s_waitcnt vmcnt(12)" ::: "memory");   // drain B(0); A(1)+B(1) fly
    __builtin_amdgcn_sched_barrier(0);
    asm volatile("s_waitcnt lgkmcnt(0)" ::: "memory");
    __builtin_amdgcn_sched_barrier(0);
    __builtin_amdgcn_s_barrier();
  } else {
    stage_half(0, 0); stage_half(0, 1); stage_half(0, 2); stage_half(0, 3);
    stage_half(1, 2); stage_half(1, 3);
    asm volatile("s_waitcnt vmcnt(4)" ::: "memory");   // A(0)+B(0) landed
    __builtin_amdgcn_sched_barrier(0);
    __builtin_amdgcn_s_barrier();
  }

  #pragma unroll 1
  for (int tt = 0; tt < NT; tt += 2) {
    tile_body(tt,     aregE, aregO);   // even t: issue A(t+2)->E, write A(t+1) from O
    tile_body(tt + 1, aregO, aregE);   // odd  t: issue A(t+2)->O, write A(t+1) from E
  }

  // ---- epilogue: coalesced C stores via wave-private LDS bounce ----
  float* wsc = (float*)As + wave * (16 * 68);
  #pragma unroll
  for (int m = 0; m < 8; ++m) {
    #pragma unroll
    for (int n = 0; n < 4; ++n)
      #pragma unroll
      for (int r = 0; r < 4; ++r)
        wsc[(lg * 4 + r) * 68 + n * 16 + li] = acc[m][n][r] + bv[n];
    asm volatile("s_waitcnt lgkmcnt(0)" ::: "memory");
    __builtin_amdgcn_sched_barrier(0);
    #pragma unroll
    for (int i = 0; i < 4; ++i) {
      int slot = i * 64 + lane;
      int r = slot >> 4, g = slot & 15;
      f32x4 vv = *(const f32x4*)(wsc + r * 68 + g * 4);
      long grow = arow0 + wr * 128 + m * 16 + r;
      long gcol = bcol0 + wc * 64 + g * 4;
      if constexpr (C_F32) {
        *(f32x4*)((float*)Cp + grow * 1024 + gcol) = vv;
      } else {
        u32x2 o;
        o[0] = cvtpk(vv[0], vv[1]);
        o[1] = cvtpk(vv[2], vv[3]);
        *(u32x2*)((unsigned short*)Cp + grow * 1024 + gcol) = o;
      }
    }
    asm volatile("s_waitcnt lgkmcnt(0)" ::: "memory");   // reads done before overwrite
    __builtin_amdgcn_sched_barrier(0);
  }
}

// Three projections batched via blockIdx.z; A operands are the RAW fp32 inputs.
__global__ __launch_bounds__(512, 2)
void gemm_proj(const float* __restrict__ A0, const float* __restrict__ A1,
               const float* __restrict__ A2,
               const unsigned short* __restrict__ B0, const unsigned short* __restrict__ B1,
               const unsigned short* __restrict__ B2,
               const float* __restrict__ b0, const float* __restrict__ b1,
               const float* __restrict__ b2,
               unsigned short* __restrict__ C0, unsigned short* __restrict__ C1,
               unsigned short* __restrict__ C2) {
  const int z = blockIdx.z;
  const float* Ap          = z == 0 ? A0 : z == 1 ? A1 : A2;
  const unsigned short* Bp = z == 0 ? B0 : z == 1 ? B1 : B2;
  const float* bias        = z == 0 ? b0 : z == 1 ? b1 : b2;
  unsigned short* Cp       = z == 0 ? C0 : z == 1 ? C1 : C2;
  gemm_core<true, false>(Ap, Bp, bias, Cp);
}

__global__ __launch_bounds__(512, 2)
void gemm_out(const unsigned short* __restrict__ Ap, const unsigned short* __restrict__ Bp,
              const float* __restrict__ bias, float* __restrict__ Cp) {
  gemm_core<false, true>(Ap, Bp, bias, Cp);
}

// ---------------- block-local attention per (b,h,c), T2-swizzled (round 8) ----
__global__ __launch_bounds__(256)
void attn_kernel(const unsigned short* __restrict__ Qp, const unsigned short* __restrict__ Kp,
                 const unsigned short* __restrict__ Vp, unsigned short* __restrict__ Cc) {
  const int bid = blockIdx.x;
  const int c = bid & 63, h = (bid >> 6) & 15, b = bid >> 10;
  const int tid = threadIdx.x;
  const int lane = tid & 63, wave = tid >> 6;
  const int lg = lane >> 4, li = lane & 15;

  __shared__ __align__(16) unsigned short Qs[128 * 64];
  __shared__ __align__(16) unsigned short Ks[128 * 64];
  __shared__ __align__(16) unsigned short Vs[128 * 64];
  __shared__ __align__(16) unsigned short Ps[4][32 * 128];

  const long base = ((long)(b * 8192 + c * 128)) * 1024 + h * 64;
  #pragma unroll
  for (int it = 0; it < 4; ++it) {
    int slot = it * 256 + tid;
    int row = slot >> 3;
    int colsw = ((slot & 7) ^ (row & 7)) * 8;      // swizzled source (Q,K)
    int collin = (slot & 7) * 8;                   // linear source (V)
    gload16(Qp + base + (long)row * 1024 + colsw, (unsigned char*)Qs + slot * 16);
    gload16(Kp + base + (long)row * 1024 + colsw, (unsigned char*)Ks + slot * 16);
    gload16(Vp + base + (long)row * 1024 + collin, (unsigned char*)Vs + slot * 16);
  }
  __syncthreads();

  f32x4 sc[2][8];
  #pragma unroll
  for (int m = 0; m < 2; ++m)
    #pragma unroll
    for (int n = 0; n < 8; ++n) sc[m][n] = (f32x4){0.f, 0.f, 0.f, 0.f};

  short8 qf[2][2];
  #pragma unroll
  for (int m = 0; m < 2; ++m)
    #pragma unroll
    for (int ks = 0; ks < 2; ++ks)
      qf[m][ks] = *(const short8*)(Qs + (wave * 32 + m * 16 + li) * 64 +
                                   (((ks * 4 + lg) ^ (li & 7)) * 8));

  #pragma unroll
  for (int n = 0; n < 8; ++n) {
    short8 kf0 = *(const short8*)(Ks + (n * 16 + li) * 64 + ((lg ^ (li & 7)) * 8));
    short8 kf1 = *(const short8*)(Ks + (n * 16 + li) * 64 + (((4 + lg) ^ (li & 7)) * 8));
    #pragma unroll
    for (int m = 0; m < 2; ++m) {
      sc[m][n] = __builtin_amdgcn_mfma_f32_16x16x32_bf16(qf[m][0], kf0, sc[m][n], 0, 0, 0);
      sc[m][n] = __builtin_amdgcn_mfma_f32_16x16x32_bf16(qf[m][1], kf1, sc[m][n], 0, 0, 0);
    }
  }

  #pragma unroll
  for (int m = 0; m < 2; ++m)
    #pragma unroll
    for (int r = 0; r < 4; ++r) {
      float mx = sc[m][0][r];
      #pragma unroll
      for (int n = 1; n < 8; ++n) mx = fmaxf(mx, sc[m][n][r]);
      #pragma unroll
      for (int d = 1; d < 16; d <<= 1) mx = fmaxf(mx, __shfl_xor(mx, d));
      float sum = 0.f;
      #pragma unroll
      for (int n = 0; n < 8; ++n) {
        float p = __expf((sc[m][n][r] - mx) * 0.125f);  // scale 1/sqrt(64)
        sc[m][n][r] = p;
        sum += p;
      }
      #pragma unroll
      for (int d = 1; d < 16; d <<= 1) sum += __shfl_xor(sum, d);
      float rinv = 1.f / sum;
      #pragma unroll
      for (int n = 0; n < 8; ++n) sc[m][n][r] *= rinv;
    }

  #pragma unroll
  for (int m = 0; m < 2; ++m)
    #pragma unroll
    for (int n = 0; n < 8; ++n)
      #pragma unroll
      for (int r = 0; r < 4; ++r) {
        int row = m * 16 + lg * 4 + r;
        int col = n * 16 + li;
        Ps[wave][row * 128 + (((col >> 3) ^ (row & 7)) * 8) + (col & 7)] = f2bf(sc[m][n][r]);
      }
  __syncthreads();

  f32x4 oc[2][4];
  #pragma unroll
  for (int m = 0; m < 2; ++m)
    #pragma unroll
    for (int n = 0; n < 4; ++n) oc[m][n] = (f32x4){0.f, 0.f, 0.f, 0.f};

  #pragma unroll
  for (int ks = 0; ks < 4; ++ks) {
    short8 vf[4];
    #pragma unroll
    for (int n = 0; n < 4; ++n)
      #pragma unroll
      for (int j = 0; j < 8; ++j)
        vf[n][j] = (short)Vs[(ks * 32 + lg * 8 + j) * 64 + n * 16 + li];
    #pragma unroll
    for (int m = 0; m < 2; ++m) {
      short8 pf = *(const short8*)(Ps[wave] + (m * 16 + li) * 128 +
                                   (((ks * 4 + lg) ^ (li & 7)) * 8));
      #pragma unroll
      for (int n = 0; n < 4; ++n)
        oc[m][n] = __builtin_amdgcn_mfma_f32_16x16x32_bf16(pf, vf[n], oc[m][n], 0, 0, 0);
    }
  }

  #pragma unroll
  for (int m = 0; m < 2; ++m)
    #pragma unroll
    for (int n = 0; n < 4; ++n)
      #pragma unroll
      for (int r = 0; r < 4; ++r) {
        int p = wave * 32 + m * 16 + lg * 4 + r;
        int d = n * 16 + li;
        int s = c * 128 + h * 8 + (p >> 4);
        int colo = (p & 15) * 64 + d;
        Cc[((long)(b * 8192 + s)) * 1024 + colo] = f2bf(oc[m][n][r]);
      }
}

extern "C" void kernel_launch(void* const* d_in, const int* in_sizes, int n_in,
                              void* d_out, int out_size, void* d_ws, size_t ws_size,
                              hipStream_t stream) {
  (void)in_sizes; (void)n_in; (void)out_size; (void)ws_size;
  const float* q  = (const float*)d_in[0];
  const float* k  = (const float*)d_in[1];
  const float* v  = (const float*)d_in[2];
  const float* WQ = (const float*)d_in[3];
  const float* bQ = (const float*)d_in[4];
  const float* WK = (const float*)d_in[5];
  const float* bK = (const float*)d_in[6];
  const float* WV = (const float*)d_in[7];
  const float* bV = (const float*)d_in[8];
  const float* WO = (const float*)d_in[9];
  const float* bO = (const float*)d_in[10];

  // ws layout: Qp | Kp | Vp | Cc (each 64MB bf16) + bf16 weights
  const size_t MN = 32768ull * 1024ull;
  unsigned short* Qp  = (unsigned short*)d_ws;
  unsigned short* Kp  = Qp + MN;
  unsigned short* Vp  = Kp + MN;
  unsigned short* Cc  = Vp + MN;
  unsigned short* WQb = Cc + MN;
  unsigned short* WKb = WQb + (1 << 20);
  unsigned short* WVb = WKb + (1 << 20);
  unsigned short* WOb = WVb + (1 << 20);

  dim3 gw(1024, 1, 4);
  f2b4_kernel<<<gw, 256, 0, stream>>>(WQ, WK, WV, WO, WQb, WKb, WVb, WOb, 1 << 20);

  dim3 gp(4, 128, 3);   // 3 projections batched; 512 blocks per z-slice
  gemm_proj<<<gp, 512, 0, stream>>>(q, k, v, WQb, WKb, WVb, bQ, bK, bV, Qp, Kp, Vp);

  attn_kernel<<<4096, 256, 0, stream>>>(Qp, Kp, Vp, Cc);

  dim3 go(4, 128);
  gemm_out<<<go, 512, 0, stream>>>(Cc, WOb, bO, (float*)d_out);
}

// Round 12
// 471.409 us; speedup vs baseline: 1.8832x; 1.8832x over previous
//
#include <hip/hip_runtime.h>
#include <hip/hip_bf16.h>

// Shapes (fixed): B=4, S=8192, D_MODEL=1024, NHEAD=16, D_K=64, D_CHUNK=128,
// C=64 chunks. M = B*S = 32768 rows for all GEMMs, K=N=1024.

typedef __attribute__((ext_vector_type(8))) short short8;   // 8 bf16 (MFMA A/B frag)
typedef __attribute__((ext_vector_type(4))) float f32x4;    // MFMA C/D frag
typedef __attribute__((ext_vector_type(4))) unsigned short us4;
typedef __attribute__((ext_vector_type(4))) unsigned int u32x4;
typedef __attribute__((ext_vector_type(2))) unsigned int u32x2;

__device__ __forceinline__ unsigned short f2bf(float f) {
  unsigned u = __float_as_uint(f);
  u += 0x7fffu + ((u >> 16) & 1u);          // RNE round to bf16
  return (unsigned short)(u >> 16);
}

// HW packed convert: low16 = bf16(lo), high16 = bf16(hi).
__device__ __forceinline__ unsigned cvtpk(float lo, float hi) {
  unsigned r;
  asm("v_cvt_pk_bf16_f32 %0, %1, %2" : "=v"(r) : "v"(lo), "v"(hi));
  return r;
}

__device__ __forceinline__ void gload16(const void* g, void* l) {
  __builtin_amdgcn_global_load_lds((const __attribute__((address_space(1))) void*)g,
                                   (__attribute__((address_space(3))) void*)l, 16, 0, 0);
}

// ---------------- fp32 -> bf16 (4 weight matrices, one dispatch) ----------------
__global__ void f2b4_kernel(const float* __restrict__ i0, const float* __restrict__ i1,
                            const float* __restrict__ i2, const float* __restrict__ i3,
                            unsigned short* __restrict__ o0, unsigned short* __restrict__ o1,
                            unsigned short* __restrict__ o2, unsigned short* __restrict__ o3,
                            int n) {
  const int z = blockIdx.z;
  const float* in = z == 0 ? i0 : z == 1 ? i1 : z == 2 ? i2 : i3;
  unsigned short* out = z == 0 ? o0 : z == 1 ? o1 : z == 2 ? o2 : o3;
  int i = (blockIdx.x * 256 + threadIdx.x) * 4;
  if (i >= n) return;
  f32x4 x = *(const f32x4*)(in + i);
  u32x2 o;
  o[0] = cvtpk(x[0], x[1]);
  o[1] = cvtpk(x[2], x[3]);
  *(u32x2*)(out + i) = o;
}

// ---------------- GEMM core: C[M,1024] = A[M,1024] * B[1024,1024]^T + bias ----
// 256x256 tile, BK=64, 512 threads = 8 waves (2M x 4N), per-wave output 128x64.
// 8-phase schedule. Per K-tile t: 4 phases x {ds_read subtile; stage;
// s_barrier; setprio(1); 16 MFMA; setprio(0); s_barrier}.
//
// A_F32=false (round-8 proven): A(t+1) via global_load_lds at P0/P1; B(t+2)
// at P2/P3; counted vmcnt(4) at P3 drains A(t+1), leaves B(t+2) in flight.
//
// A_F32=true (fused fp32->bf16, HALF-ROTATED single-buffer prefetch —
// round-11's depth-2 spilled to scratch at +32 VGPRs, this gets the same
// latency cover at round-10's register cost):
//   t.P2: [stage B-lo(t+2) pre-barrier] MFMA; writeAh(t+1,0) (dep-wait on
//         A-lo(t+1), issued at (t-1).P2 -> 4 phases ~700cyc cover; FIFO
//         drain covers B-lo(t+1) which was issued just before it);
//         issueA_half(t+2,0) into the 16 VGPRs writeAh just freed (WAR on
//         the registers orders the loads after the reads).
//   t.P3: same for the hi half; then lgkmcnt(0) publishes A(t+1) before the
//         closing barrier. Steady-state issue order per tile is
//         {B-lo, A-lo, B-hi, A-hi} so the two dep-waits drain B(t+1)
//         entirely — NO manual vmcnt in the loop. Prologue establishes the
//         invariant with one vmcnt(12). Tails verified (t=NT-2: issues
//         skipped, drains still via deps; t=NT-1: writes skipped).
// T2: LDS dest linear; XOR swizzle g^(row&7) on the GLOBAL source granule
// and identically on ds_read (rule 21). Epilogue: coalesced C stores via
// wave-private LDS bounce.
template<bool A_F32, bool C_F32>
__device__ __forceinline__ void gemm_core(const void* __restrict__ Apv,
                                          const unsigned short* __restrict__ Bp,
                                          const float* __restrict__ bias,
                                          void* __restrict__ Cp) {
  constexpr int BK = 64, NT = 16;
  const int tid = threadIdx.x;              // 0..511
  const int lane = tid & 63, wave = tid >> 6;
  const int lg = lane >> 4, li = lane & 15;
  const int wr = wave >> 2, wc = wave & 3;  // 2 x 4 wave grid

  const unsigned short* Ab = (const unsigned short*)Apv;  // bf16 path
  const float* Af = (const float*)Apv;                    // fp32 path

  // XCD swizzle (nwg = 512, divisible by 8 -> bijective).
  const int orig = blockIdx.y * 4 + blockIdx.x;
  const int wg = (orig & 7) * 64 + (orig >> 3);
  const int bn = wg & 3, bm = wg >> 2;

  const long arow0 = (long)bm * 256;
  const int bcol0 = bn * 256;

  __shared__ __align__(16) unsigned short As[2][256 * BK];  // 64 KB
  __shared__ __align__(16) unsigned short Bs[2][256 * BK];  // 64 KB

  float bv[4];
  #pragma unroll
  for (int n = 0; n < 4; ++n) bv[n] = bias[bcol0 + wc * 64 + n * 16 + li];

  f32x4 acc[8][4];
  #pragma unroll
  for (int m = 0; m < 8; ++m)
    #pragma unroll
    for (int n = 0; n < 4; ++n) acc[m][n] = (f32x4){0.f, 0.f, 0.f, 0.f};

  // Stage one half-tile via global_load_lds: h = 0:A-lo 1:A-hi 2:B-lo 3:B-hi.
  auto stage_half = [&](int u, int h) {
    const int k0 = u * BK;
    const int half = h & 1;
    unsigned short* dst = (h < 2 ? As[u & 1] : Bs[u & 1]) + half * (128 * BK);
    const unsigned short* src = (h < 2) ? Ab : Bp;
    const long rbase = (h < 2) ? (arow0 + half * 128) : (long)(bcol0 + half * 128);
    #pragma unroll
    for (int it = 0; it < 2; ++it) {
      int s = it * 512 + tid;              // 0..1023
      int row = s >> 3;
      int eg = ((s & 7) ^ (row & 7)) * 8;  // pre-swizzled source granule
      gload16(src + (rbase + row) * 1024 + k0 + eg, (unsigned char*)dst + s * 16);
    }
  };

  // fp32-A register staging, SINGLE buffer rotated by halves (rule 20: hf is
  // always a literal -> static indexing; no scratch).
  f32x4 areg[4][2];
  auto issueA_half = [&](int u, int hf) {
    #pragma unroll
    for (int it = 0; it < 2; ++it) {
      int s = it * 512 + tid;
      int row = s >> 3;
      int ce = ((s & 7) ^ (row & 7)) * 8;
      const float* p = Af + (arow0 + hf * 128 + row) * 1024 + u * BK + ce;
      areg[hf * 2 + it][0] = *(const f32x4*)p;
      areg[hf * 2 + it][1] = *(const f32x4*)(p + 4);
    }
  };
  // 8 cvt_pk + 2 ds_write_b128 per half.
  auto writeAh = [&](int u, int hf) {
    unsigned short* dstb = As[u & 1] + hf * (128 * BK);
    #pragma unroll
    for (int it = 0; it < 2; ++it) {
      int s = it * 512 + tid;
      u32x4 o;
      o[0] = cvtpk(areg[hf * 2 + it][0][0], areg[hf * 2 + it][0][1]);
      o[1] = cvtpk(areg[hf * 2 + it][0][2], areg[hf * 2 + it][0][3]);
      o[2] = cvtpk(areg[hf * 2 + it][1][0], areg[hf * 2 + it][1][1]);
      o[3] = cvtpk(areg[hf * 2 + it][1][2], areg[hf * 2 + it][1][3]);
      *(u32x4*)((unsigned char*)dstb + s * 16) = o;
    }
  };

  // ---- prologue ----
  if constexpr (A_F32) {
    issueA_half(0, 0); issueA_half(0, 1); // A(0) 8 loads (oldest)
    stage_half(0, 2); stage_half(0, 3);   // B(0) 4
    writeAh(0, 0); writeAh(0, 1);         // dep-waits drain A(0)
    // Steady-state issue order for tile 1: B-lo, A-lo, B-hi, A-hi.
    stage_half(1, 2);                     // B-lo(1) 2
    issueA_half(1, 0);                    // A-lo(1) 4
    stage_half(1, 3);                     // B-hi(1) 2
    issueA_half(1, 1);                    // A-hi(1) 4
    asm volatile("s_waitcnt vmcnt(12)" ::: "memory");   // drain B(0); 12 fly
    __builtin_amdgcn_sched_barrier(0);
    asm volatile("s_waitcnt lgkmcnt(0)" ::: "memory");  // publish A(0)
    __builtin_amdgcn_sched_barrier(0);
    __builtin_amdgcn_s_barrier();
  } else {
    stage_half(0, 0); stage_half(0, 1); stage_half(0, 2); stage_half(0, 3);
    stage_half(1, 2); stage_half(1, 3);
    asm volatile("s_waitcnt vmcnt(4)" ::: "memory");   // A(0)+B(0) landed
    __builtin_amdgcn_sched_barrier(0);
    __builtin_amdgcn_s_barrier();
  }

  for (int t = 0; t < NT; ++t) {
    const unsigned short* Asb = As[t & 1];
    const unsigned short* Bsb = Bs[t & 1];

    auto LDA = [&](int m, int kk) {
      return *(const short8*)(Asb + (wr * 128 + m * 16 + li) * BK +
                              (((kk * 4 + lg) ^ (li & 7)) * 8));
    };
    auto LDB = [&](int n, int kk) {
      return *(const short8*)(Bsb + (wc * 64 + n * 16 + li) * BK +
                              (((kk * 4 + lg) ^ (li & 7)) * 8));
    };

    short8 b0[4], b1[4];

    // ---- P0 ----
    {
      short8 a0[4];
      #pragma unroll
      for (int i = 0; i < 4; ++i) a0[i] = LDA(i, 0);
      #pragma unroll
      for (int n = 0; n < 4; ++n) b0[n] = LDB(n, 0);
      if constexpr (!A_F32) {
        if (t + 1 < NT) stage_half(t + 1, 0);
      }
      __builtin_amdgcn_s_barrier();
      __builtin_amdgcn_s_setprio(1);
      #pragma unroll
      for (int i = 0; i < 4; ++i)
        #pragma unroll
        for (int n = 0; n < 4; ++n)
          acc[i][n] = __builtin_amdgcn_mfma_f32_16x16x32_bf16(a0[i], b0[n], acc[i][n], 0, 0, 0);
      __builtin_amdgcn_s_setprio(0);
      __builtin_amdgcn_s_barrier();
    }
    // ---- P1 ----
    {
      short8 a1[4];
      #pragma unroll
      for (int i = 0; i < 4; ++i) a1[i] = LDA(i, 1);
      #pragma unroll
      for (int n = 0; n < 4; ++n) b1[n] = LDB(n, 1);
      if constexpr (!A_F32) {
        if (t + 1 < NT) stage_half(t + 1, 1);
      }
      __builtin_amdgcn_s_barrier();
      __builtin_amdgcn_s_setprio(1);
      #pragma unroll
      for (int i = 0; i < 4; ++i)
        #pragma unroll
        for (int n = 0; n < 4; ++n)
          acc[i][n] = __builtin_amdgcn_mfma_f32_16x16x32_bf16(a1[i], b1[n], acc[i][n], 0, 0, 0);
      __builtin_amdgcn_s_setprio(0);
      __builtin_amdgcn_s_barrier();
    }
    // ---- P2 ----
    {
      short8 a2[4];
      #pragma unroll
      for (int i = 0; i < 4; ++i) a2[i] = LDA(4 + i, 0);
      if (t + 2 < NT) stage_half(t + 2, 2);      // B-lo(t+2)
      __builtin_amdgcn_s_barrier();
      __builtin_amdgcn_s_setprio(1);
      #pragma unroll
      for (int i = 0; i < 4; ++i)
        #pragma unroll
        for (int n = 0; n < 4; ++n)
          acc[4 + i][n] = __builtin_amdgcn_mfma_f32_16x16x32_bf16(a2[i], b0[n], acc[4 + i][n], 0, 0, 0);
      if constexpr (A_F32) {
        if (t + 1 < NT) writeAh(t + 1, 0);       // dep drains B-lo(t+1)+A-lo(t+1)
        if (t + 2 < NT) issueA_half(t + 2, 0);   // reuses freed regs (WAR-ordered)
      }
      __builtin_amdgcn_s_setprio(0);
      __builtin_amdgcn_s_barrier();
    }
    // ---- P3 ----
    {
      short8 a3[4];
      #pragma unroll
      for (int i = 0; i < 4; ++i) a3[i] = LDA(4 + i, 1);
      if (t + 2 < NT) stage_half(t + 2, 3);      // B-hi(t+2)
      if constexpr (!A_F32) {
        if (t + 2 < NT) {
          asm volatile("s_waitcnt vmcnt(4)" ::: "memory");   // A(t+1) landed
        } else {
          asm volatile("s_waitcnt vmcnt(0)" ::: "memory");
        }
        __builtin_amdgcn_sched_barrier(0);
      }
      __builtin_amdgcn_s_barrier();
      __builtin_amdgcn_s_setprio(1);
      #pragma unroll
      for (int i = 0; i < 4; ++i)
        #pragma unroll
        for (int n = 0; n < 4; ++n)
          acc[4 + i][n] = __builtin_amdgcn_mfma_f32_16x16x32_bf16(a3[i], b1[n], acc[4 + i][n], 0, 0, 0);
      if constexpr (A_F32) {
        if (t + 1 < NT) {
          writeAh(t + 1, 1);                     // dep drains B-hi(t+1)+A-hi(t+1)
          if (t + 2 < NT) issueA_half(t + 2, 1);
          asm volatile("s_waitcnt lgkmcnt(0)" ::: "memory");   // publish A(t+1)
          __builtin_amdgcn_sched_barrier(0);
        }
      }
      __builtin_amdgcn_s_setprio(0);
      __builtin_amdgcn_s_barrier();              // closing: tile t+1 ready
    }
  }

  // ---- epilogue: coalesced C stores via wave-private LDS bounce ----
  float* wsc = (float*)As + wave * (16 * 68);
  #pragma unroll
  for (int m = 0; m < 8; ++m) {
    #pragma unroll
    for (int n = 0; n < 4; ++n)
      #pragma unroll
      for (int r = 0; r < 4; ++r)
        wsc[(lg * 4 + r) * 68 + n * 16 + li] = acc[m][n][r] + bv[n];
    asm volatile("s_waitcnt lgkmcnt(0)" ::: "memory");
    __builtin_amdgcn_sched_barrier(0);
    #pragma unroll
    for (int i = 0; i < 4; ++i) {
      int slot = i * 64 + lane;
      int r = slot >> 4, g = slot & 15;
      f32x4 vv = *(const f32x4*)(wsc + r * 68 + g * 4);
      long grow = arow0 + wr * 128 + m * 16 + r;
      long gcol = bcol0 + wc * 64 + g * 4;
      if constexpr (C_F32) {
        *(f32x4*)((float*)Cp + grow * 1024 + gcol) = vv;
      } else {
        u32x2 o;
        o[0] = cvtpk(vv[0], vv[1]);
        o[1] = cvtpk(vv[2], vv[3]);
        *(u32x2*)((unsigned short*)Cp + grow * 1024 + gcol) = o;
      }
    }
    asm volatile("s_waitcnt lgkmcnt(0)" ::: "memory");   // reads done before overwrite
    __builtin_amdgcn_sched_barrier(0);
  }
}

// Three projections batched via blockIdx.z; A operands are the RAW fp32 inputs.
__global__ __launch_bounds__(512, 2)
void gemm_proj(const float* __restrict__ A0, const float* __restrict__ A1,
               const float* __restrict__ A2,
               const unsigned short* __restrict__ B0, const unsigned short* __restrict__ B1,
               const unsigned short* __restrict__ B2,
               const float* __restrict__ b0, const float* __restrict__ b1,
               const float* __restrict__ b2,
               unsigned short* __restrict__ C0, unsigned short* __restrict__ C1,
               unsigned short* __restrict__ C2) {
  const int z = blockIdx.z;
  const float* Ap          = z == 0 ? A0 : z == 1 ? A1 : A2;
  const unsigned short* Bp = z == 0 ? B0 : z == 1 ? B1 : B2;
  const float* bias        = z == 0 ? b0 : z == 1 ? b1 : b2;
  unsigned short* Cp       = z == 0 ? C0 : z == 1 ? C1 : C2;
  gemm_core<true, false>(Ap, Bp, bias, Cp);
}

__global__ __launch_bounds__(512, 2)
void gemm_out(const unsigned short* __restrict__ Ap, const unsigned short* __restrict__ Bp,
              const float* __restrict__ bias, float* __restrict__ Cp) {
  gemm_core<false, true>(Ap, Bp, bias, Cp);
}

// ---------------- block-local attention per (b,h,c), T2-swizzled (round 8) ----
__global__ __launch_bounds__(256)
void attn_kernel(const unsigned short* __restrict__ Qp, const unsigned short* __restrict__ Kp,
                 const unsigned short* __restrict__ Vp, unsigned short* __restrict__ Cc) {
  const int bid = blockIdx.x;
  const int c = bid & 63, h = (bid >> 6) & 15, b = bid >> 10;
  const int tid = threadIdx.x;
  const int lane = tid & 63, wave = tid >> 6;
  const int lg = lane >> 4, li = lane & 15;

  __shared__ __align__(16) unsigned short Qs[128 * 64];
  __shared__ __align__(16) unsigned short Ks[128 * 64];
  __shared__ __align__(16) unsigned short Vs[128 * 64];
  __shared__ __align__(16) unsigned short Ps[4][32 * 128];

  const long base = ((long)(b * 8192 + c * 128)) * 1024 + h * 64;
  #pragma unroll
  for (int it = 0; it < 4; ++it) {
    int slot = it * 256 + tid;
    int row = slot >> 3;
    int colsw = ((slot & 7) ^ (row & 7)) * 8;      // swizzled source (Q,K)
    int collin = (slot & 7) * 8;                   // linear source (V)
    gload16(Qp + base + (long)row * 1024 + colsw, (unsigned char*)Qs + slot * 16);
    gload16(Kp + base + (long)row * 1024 + colsw, (unsigned char*)Ks + slot * 16);
    gload16(Vp + base + (long)row * 1024 + collin, (unsigned char*)Vs + slot * 16);
  }
  __syncthreads();

  f32x4 sc[2][8];
  #pragma unroll
  for (int m = 0; m < 2; ++m)
    #pragma unroll
    for (int n = 0; n < 8; ++n) sc[m][n] = (f32x4){0.f, 0.f, 0.f, 0.f};

  short8 qf[2][2];
  #pragma unroll
  for (int m = 0; m < 2; ++m)
    #pragma unroll
    for (int ks = 0; ks < 2; ++ks)
      qf[m][ks] = *(const short8*)(Qs + (wave * 32 + m * 16 + li) * 64 +
                                   (((ks * 4 + lg) ^ (li & 7)) * 8));

  #pragma unroll
  for (int n = 0; n < 8; ++n) {
    short8 kf0 = *(const short8*)(Ks + (n * 16 + li) * 64 + ((lg ^ (li & 7)) * 8));
    short8 kf1 = *(const short8*)(Ks + (n * 16 + li) * 64 + (((4 + lg) ^ (li & 7)) * 8));
    #pragma unroll
    for (int m = 0; m < 2; ++m) {
      sc[m][n] = __builtin_amdgcn_mfma_f32_16x16x32_bf16(qf[m][0], kf0, sc[m][n], 0, 0, 0);
      sc[m][n] = __builtin_amdgcn_mfma_f32_16x16x32_bf16(qf[m][1], kf1, sc[m][n], 0, 0, 0);
    }
  }

  #pragma unroll
  for (int m = 0; m < 2; ++m)
    #pragma unroll
    for (int r = 0; r < 4; ++r) {
      float mx = sc[m][0][r];
      #pragma unroll
      for (int n = 1; n < 8; ++n) mx = fmaxf(mx, sc[m][n][r]);
      #pragma unroll
      for (int d = 1; d < 16; d <<= 1) mx = fmaxf(mx, __shfl_xor(mx, d));
      float sum = 0.f;
      #pragma unroll
      for (int n = 0; n < 8; ++n) {
        float p = __expf((sc[m][n][r] - mx) * 0.125f);  // scale 1/sqrt(64)
        sc[m][n][r] = p;
        sum += p;
      }
      #pragma unroll
      for (int d = 1; d < 16; d <<= 1) sum += __shfl_xor(sum, d);
      float rinv = 1.f / sum;
      #pragma unroll
      for (int n = 0; n < 8; ++n) sc[m][n][r] *= rinv;
    }

  #pragma unroll
  for (int m = 0; m < 2; ++m)
    #pragma unroll
    for (int n = 0; n < 8; ++n)
      #pragma unroll
      for (int r = 0; r < 4; ++r) {
        int row = m * 16 + lg * 4 + r;
        int col = n * 16 + li;
        Ps[wave][row * 128 + (((col >> 3) ^ (row & 7)) * 8) + (col & 7)] = f2bf(sc[m][n][r]);
      }
  __syncthreads();

  f32x4 oc[2][4];
  #pragma unroll
  for (int m = 0; m < 2; ++m)
    #pragma unroll
    for (int n = 0; n < 4; ++n) oc[m][n] = (f32x4){0.f, 0.f, 0.f, 0.f};

  #pragma unroll
  for (int ks = 0; ks < 4; ++ks) {
    short8 vf[4];
    #pragma unroll
    for (int n = 0; n < 4; ++n)
      #pragma unroll
      for (int j = 0; j < 8; ++j)
        vf[n][j] = (short)Vs[(ks * 32 + lg * 8 + j) * 64 + n * 16 + li];
    #pragma unroll
    for (int m = 0; m < 2; ++m) {
      short8 pf = *(const short8*)(Ps[wave] + (m * 16 + li) * 128 +
                                   (((ks * 4 + lg) ^ (li & 7)) * 8));
      #pragma unroll
      for (int n = 0; n < 4; ++n)
        oc[m][n] = __builtin_amdgcn_mfma_f32_16x16x32_bf16(pf, vf[n], oc[m][n], 0, 0, 0);
    }
  }

  #pragma unroll
  for (int m = 0; m < 2; ++m)
    #pragma unroll
    for (int n = 0; n < 4; ++n)
      #pragma unroll
      for (int r = 0; r < 4; ++r) {
        int p = wave * 32 + m * 16 + lg * 4 + r;
        int d = n * 16 + li;
        int s = c * 128 + h * 8 + (p >> 4);
        int colo = (p & 15) * 64 + d;
        Cc[((long)(b * 8192 + s)) * 1024 + colo] = f2bf(oc[m][n][r]);
      }
}

extern "C" void kernel_launch(void* const* d_in, const int* in_sizes, int n_in,
                              void* d_out, int out_size, void* d_ws, size_t ws_size,
                              hipStream_t stream) {
  (void)in_sizes; (void)n_in; (void)out_size; (void)ws_size;
  const float* q  = (const float*)d_in[0];
  const float* k  = (const float*)d_in[1];
  const float* v  = (const float*)d_in[2];
  const float* WQ = (const float*)d_in[3];
  const float* bQ = (const float*)d_in[4];
  const float* WK = (const float*)d_in[5];
  const float* bK = (const float*)d_in[6];
  const float* WV = (const float*)d_in[7];
  const float* bV = (const float*)d_in[8];
  const float* WO = (const float*)d_in[9];
  const float* bO = (const float*)d_in[10];

  // ws layout: Qp | Kp | Vp | Cc (each 64MB bf16) + bf16 weights
  const size_t MN = 32768ull * 1024ull;
  unsigned short* Qp  = (unsigned short*)d_ws;
  unsigned short* Kp  = Qp + MN;
  unsigned short* Vp  = Kp + MN;
  unsigned short* Cc  = Vp + MN;
  unsigned short* WQb = Cc + MN;
  unsigned short* WKb = WQb + (1 << 20);
  unsigned short* WVb = WKb + (1 << 20);
  unsigned short* WOb = WVb + (1 << 20);

  dim3 gw(1024, 1, 4);
  f2b4_kernel<<<gw, 256, 0, stream>>>(WQ, WK, WV, WO, WQb, WKb, WVb, WOb, 1 << 20);

  dim3 gp(4, 128, 3);   // 3 projections batched; 512 blocks per z-slice
  gemm_proj<<<gp, 512, 0, stream>>>(q, k, v, WQb, WKb, WVb, bQ, bK, bV, Qp, Kp, Vp);

  attn_kernel<<<4096, 256, 0, stream>>>(Qp, Kp, Vp, Cc);

  dim3 go(4, 128);
  gemm_out<<<go, 512, 0, stream>>>(Cc, WOb, bO, (float*)d_out);
}